// Round 10
// baseline (34.431 us; speedup 1.0000x reference)
//
#include <hip/hip_runtime.h>

#define BINS 10
#define BLOCK 256
#define GRID 2048
#define NCOPY 8            // atomic striping factor
#define CSTRIDE 32         // doubles per copy (256 B -> distinct cache lines)

#define LOG2E 1.44269504088896340736f
#define LN2   0.6931471805599453094

// ---------------------------------------------------------------------------
// For logit x with one-hot target bit tg, let y = tg ? -x : x. Then
//   g   = |sigmoid(x) - tg| = sigmoid(y) = u/(1+u),  u = e^y
//   bce = softplus(y) = ln(1+u) = ln2 * log2(1+u)
// Direct binning: b = min(int(10*sigmoid(y)), 9). Per-thread-private LDS
// histogram columns (hist[b][tid]) accumulated with plain ds_read_b64 /
// v_add / ds_write_b64 (NOT ds_add_f32 — round 5 showed LDS atomics are
// ~100 cyc/op). Column layout: addr = b*2048 + tid*8; 2048 % 128 == 0 so
// the bin never changes the bank; 64 lanes x b64 = 2 lanes/bank-pair = free.
//
// Loads are permutation-invariant (histogram!), so each wave reads
// lane-contiguous float4 (1 KiB/instr) and int2 (512 B/instr) chunks:
// perfectly coalesced, with in-lane pred/target row alignment.
//
// ws: double[NCOPY][CSTRIDE]; copy r: [0..9] counts, [10..19] log2-bce sums.
// Block b adds into copy (b & 7) -> per-address serialization 256, not 2048.
// Kernel boundary is the release point (no fences — round 8 lesson).
// ---------------------------------------------------------------------------

__global__ void ghmc_init(double* ws) {
    int i = threadIdx.x;
    if (i < NCOPY * CSTRIDE) ws[i] = 0.0;
}

__device__ __forceinline__ void proc(float y, float2* __restrict__ hcol) {
    y = fminf(fmaxf(y, -80.0f), 80.0f);              // v_med3_f32 guard
    float u  = __builtin_amdgcn_exp2f(y * LOG2E);    // e^y
    float d  = 1.0f + u;
    float r  = __builtin_amdgcn_rcpf(d);
    float lg = __builtin_amdgcn_logf(d);             // log2(1+u) = bce/ln2
    float sg = u * r;                                // sigmoid(y) = g in [0,1]
    int b = (int)(sg * 10.0f);
    b = b > (BINS - 1) ? (BINS - 1) : b;
    float2* h = hcol + (b << 8);                     // + b*BLOCK float2s
    float2 v = *h;                                   // ds_read_b64
    v.x += 1.0f;
    v.y += lg;
    *h = v;                                          // ds_write_b64
}

__device__ __forceinline__ void proc_row(float x0, float x1, int t,
                                         float2* __restrict__ hcol) {
    // class0 flips iff t==0, class1 flips iff t==1 (t in {0,1})
    unsigned s0 = (unsigned)(t ^ 1) << 31;
    unsigned s1 = s0 ^ 0x80000000u;
    proc(__uint_as_float(__float_as_uint(x0) ^ s0), hcol);
    proc(__uint_as_float(__float_as_uint(x1) ^ s1), hcol);
}

__global__ __launch_bounds__(BLOCK, 8) void ghmc_main(
    const float4* __restrict__ pred4,   // one float4 = 2 rows' logits
    const int2*   __restrict__ tgt2,    // one int2   = 2 rows' targets (int32)
    double* __restrict__ wsd,
    int nF4, int nRows)                 // nF4 = nRows/2
{
    __shared__ float2 hist[BINS][BLOCK];   // 20 KiB -> 8 blocks/CU
    const int tid = threadIdx.x;
#pragma unroll
    for (int b = 0; b < BINS; ++b) hist[b][tid] = make_float2(0.f, 0.f);
    // no sync needed: each thread touches only its own column until reduction

    float2* hcol = &hist[0][tid];

    // wave w sweeps float4s [w*256, w*256+256): 4 lane-contiguous chunks
    const int lane = tid & 63;
    const int gw   = (blockIdx.x * BLOCK + tid) >> 6;   // global wave id
    const int NW   = (GRID * BLOCK) >> 6;               // total waves

    for (int w = gw; w * 256 < nF4; w += NW) {
        int base = w * 256 + lane;
#pragma unroll
        for (int j = 0; j < 4; ++j) {
            int idx = base + j * 64;
            if (idx < nF4) {
                float4 p = pred4[idx];    // rows 2idx, 2idx+1 (coalesced 1 KiB)
                int2   t = tgt2[idx];     // same rows' targets (coalesced 512 B)
                proc_row(p.x, p.y, t.x, hcol);
                proc_row(p.z, p.w, t.y, hcol);
            }
        }
    }

    // defensive scalar tail for an odd row (nRows even here)
    if (blockIdx.x == 0 && tid == 0 && (nRows & 1)) {
        const float* pf = (const float*)pred4;
        const int*   tf = (const int*)tgt2;
        int r = nRows - 1;
        proc_row(pf[2 * r], pf[2 * r + 1], tf[r], hcol);
    }

    __syncthreads();

    // 256 -> 128 -> 64 in LDS, then wave-0 shuffle reduce
    if (tid < 128) {
#pragma unroll
        for (int b = 0; b < BINS; ++b) {
            float2 x = hist[b][tid], y = hist[b][tid + 128];
            hist[b][tid] = make_float2(x.x + y.x, x.y + y.y);
        }
    }
    __syncthreads();
    __shared__ float svals[2 * BINS];
    if (tid < 64) {
        float cx[BINS], cy[BINS];
#pragma unroll
        for (int b = 0; b < BINS; ++b) {
            float2 x = hist[b][tid], y = hist[b][tid + 64];
            cx[b] = x.x + y.x;
            cy[b] = x.y + y.y;
        }
#pragma unroll
        for (int off = 32; off > 0; off >>= 1) {
#pragma unroll
            for (int b = 0; b < BINS; ++b) {
                cx[b] += __shfl_down(cx[b], off, 64);
                cy[b] += __shfl_down(cy[b], off, 64);
            }
        }
        if (tid == 0) {
#pragma unroll
            for (int b = 0; b < BINS; ++b) {
                svals[b]        = cx[b];
                svals[BINS + b] = cy[b];
            }
        }
    }
    __syncthreads();

    // 20 device atomics per block, striped over 8 copies (256-deep per addr)
    double* wcopy = wsd + (blockIdx.x & (NCOPY - 1)) * CSTRIDE;
    if (tid < 2 * BINS) atomicAdd(&wcopy[tid], (double)svals[tid]);
    // no fence, no readback: kernel boundary is the release point
}

__global__ __launch_bounds__(64) void ghmc_fin(
    const double* __restrict__ wsd, float* __restrict__ out)
{
    const int tid = threadIdx.x;
    __shared__ double vals[2 * BINS];
    if (tid < 2 * BINS) {
        double a = 0.0;
#pragma unroll
        for (int r = 0; r < NCOPY; ++r) a += wsd[r * CSTRIDE + tid];
        vals[tid] = a;
    }
    __syncthreads();
    if (tid == 0) {
        int nz = 0;
        double acc = 0.0;
#pragma unroll
        for (int b = 0; b < BINS; ++b) {
            double cnt = vals[b];
            double sm  = vals[BINS + b] * LN2;   // log2 units -> nats
            if (cnt > 0.0) { nz++; acc += sm / cnt; }
        }
        out[0] = (float)((nz > 0) ? (acc / (double)nz) : 0.0);
    }
}

extern "C" void kernel_launch(void* const* d_in, const int* in_sizes, int n_in,
                              void* d_out, int out_size, void* d_ws, size_t ws_size,
                              hipStream_t stream) {
    const float* pred = (const float*)d_in[0];   // [N,2] float32
    const int* target = (const int*)d_in[1];     // [N] int32 (harness lowers int64)
    const int nRows = in_sizes[1];
    const int nF4 = nRows / 2;
    double* wsd = (double*)d_ws;
    float* out = (float*)d_out;

    ghmc_init<<<1, 256, 0, stream>>>(wsd);
    ghmc_main<<<GRID, BLOCK, 0, stream>>>(
        (const float4*)pred, (const int2*)target, wsd, nF4, nRows);
    ghmc_fin<<<1, 64, 0, stream>>>(wsd, out);
}

// Round 11
// 31.810 us; speedup vs baseline: 1.0824x; 1.0824x over previous
//
#include <hip/hip_runtime.h>

#define BINS 10
#define BLOCK 256
#define GRID 2048
#define NCOPY 8            // atomic striping factor
#define CSTRIDE 32         // doubles per copy (256 B -> distinct cache lines)

#define LOG2E 1.44269504088896340736f
#define LN2   0.6931471805599453094

// ---------------------------------------------------------------------------
// For logit x with one-hot target bit tg, let y = tg ? -x : x. Then
//   g   = |sigmoid(x) - tg| = sigmoid(y) = u/(1+u),  u = e^y
//   bce = softplus(y) = ln(1+u) = ln2 * log2(1+u)
// Direct binning: b = min(int(10*sigmoid(y)), 9). Per-thread-private LDS
// histogram columns (hist[b][tid]) accumulated with plain ds_read_b64 /
// v_add / ds_write_b64 (NOT ds_add_f32 — round 5: LDS atomics ~100 cyc/op).
// Column layout: addr = b*2048 + tid*8; bin stride == 0 mod banks, 2
// lanes/bank = free (m136).
//
// LDS budget is EXACTLY 20480 B (round 10 lesson: +512 B -> 7 blocks/CU and
// a 256-block straggler round at 1 block/CU). The epilogue staging reuses
// hist[0]'s row instead of a separate svals[] array. 8 blocks x 20480 B =
// 160 KiB/CU exactly; GRID = 8 x 256 CUs and 8192 waves x 2 chunks = nF4:
// perfectly balanced, single residency round.
//
// ws: double[NCOPY][CSTRIDE]; copy r: [0..9] counts, [10..19] log2-bce sums.
// Block b adds into copy (b & 7) -> per-address serialization 256, not 2048.
// Kernel boundary is the release point (no fences — round 8 lesson).
// ---------------------------------------------------------------------------

__global__ void ghmc_init(double* ws) {
    int i = threadIdx.x;
    if (i < NCOPY * CSTRIDE) ws[i] = 0.0;
}

__device__ __forceinline__ void proc(float y, float2* __restrict__ hcol) {
    y = fminf(fmaxf(y, -80.0f), 80.0f);              // v_med3_f32 guard
    float u  = __builtin_amdgcn_exp2f(y * LOG2E);    // e^y
    float d  = 1.0f + u;
    float r  = __builtin_amdgcn_rcpf(d);
    float lg = __builtin_amdgcn_logf(d);             // log2(1+u) = bce/ln2
    float sg = u * r;                                // sigmoid(y) = g in [0,1]
    int b = (int)(sg * 10.0f);
    b = b > (BINS - 1) ? (BINS - 1) : b;
    float2* h = hcol + (b << 8);                     // + b*BLOCK float2s
    float2 v = *h;                                   // ds_read_b64
    v.x += 1.0f;
    v.y += lg;
    *h = v;                                          // ds_write_b64
}

__device__ __forceinline__ void proc_row(float x0, float x1, int t,
                                         float2* __restrict__ hcol) {
    // class0 flips iff t==0, class1 flips iff t==1 (t in {0,1})
    unsigned s0 = (unsigned)(t ^ 1) << 31;
    unsigned s1 = s0 ^ 0x80000000u;
    proc(__uint_as_float(__float_as_uint(x0) ^ s0), hcol);
    proc(__uint_as_float(__float_as_uint(x1) ^ s1), hcol);
}

__global__ __launch_bounds__(BLOCK, 8) void ghmc_main(
    const float4* __restrict__ pred4,   // one float4 = 2 rows' logits
    const int2*   __restrict__ tgt2,    // one int2   = 2 rows' targets (int32)
    double* __restrict__ wsd,
    int nF4, int nRows)                 // nF4 = nRows/2
{
    __shared__ float2 hist[BINS][BLOCK];   // 20480 B EXACTLY -> 8 blocks/CU
    const int tid = threadIdx.x;
#pragma unroll
    for (int b = 0; b < BINS; ++b) hist[b][tid] = make_float2(0.f, 0.f);
    // no sync needed: each thread touches only its own column until reduction

    float2* hcol = &hist[0][tid];

    // wave w sweeps float4s [w*256, w*256+256): 4 lane-contiguous chunks
    const int lane = tid & 63;
    const int gw   = (blockIdx.x * BLOCK + tid) >> 6;   // global wave id
    const int NW   = (GRID * BLOCK) >> 6;               // total waves

    for (int w = gw; w * 256 < nF4; w += NW) {
        int base = w * 256 + lane;
#pragma unroll
        for (int j = 0; j < 4; ++j) {
            int idx = base + j * 64;
            if (idx < nF4) {
                float4 p = pred4[idx];    // rows 2idx, 2idx+1 (coalesced 1 KiB)
                int2   t = tgt2[idx];     // same rows' targets (coalesced 512 B)
                proc_row(p.x, p.y, t.x, hcol);
                proc_row(p.z, p.w, t.y, hcol);
            }
        }
    }

    // defensive scalar tail for an odd row (nRows even here)
    if (blockIdx.x == 0 && tid == 0 && (nRows & 1)) {
        const float* pf = (const float*)pred4;
        const int*   tf = (const int*)tgt2;
        int r = nRows - 1;
        proc_row(pf[2 * r], pf[2 * r + 1], tf[r], hcol);
    }

    __syncthreads();

    // 256 -> 128 -> 64 in LDS, then wave-0 shuffle reduce
    if (tid < 128) {
#pragma unroll
        for (int b = 0; b < BINS; ++b) {
            float2 x = hist[b][tid], y = hist[b][tid + 128];
            hist[b][tid] = make_float2(x.x + y.x, x.y + y.y);
        }
    }
    __syncthreads();
    if (tid < 64) {
        float cx[BINS], cy[BINS];
#pragma unroll
        for (int b = 0; b < BINS; ++b) {
            float2 x = hist[b][tid], y = hist[b][tid + 64];
            cx[b] = x.x + y.x;
            cy[b] = x.y + y.y;
        }
#pragma unroll
        for (int off = 32; off > 0; off >>= 1) {
#pragma unroll
            for (int b = 0; b < BINS; ++b) {
                cx[b] += __shfl_down(cx[b], off, 64);
                cy[b] += __shfl_down(cy[b], off, 64);
            }
        }
        if (tid == 0) {
            // stage totals in hist[0]'s (now dead) row: no extra LDS
            float* sv = (float*)&hist[0][0];
#pragma unroll
            for (int b = 0; b < BINS; ++b) {
                sv[b]        = cx[b];
                sv[BINS + b] = cy[b];
            }
        }
    }
    __syncthreads();

    // 20 device atomics per block, striped over 8 copies (256-deep per addr)
    double* wcopy = wsd + (blockIdx.x & (NCOPY - 1)) * CSTRIDE;
    const float* sv = (const float*)&hist[0][0];
    if (tid < 2 * BINS) atomicAdd(&wcopy[tid], (double)sv[tid]);
    // no fence, no readback: kernel boundary is the release point
}

__global__ __launch_bounds__(64) void ghmc_fin(
    const double* __restrict__ wsd, float* __restrict__ out)
{
    const int tid = threadIdx.x;
    __shared__ double vals[2 * BINS];
    if (tid < 2 * BINS) {
        double a = 0.0;
#pragma unroll
        for (int r = 0; r < NCOPY; ++r) a += wsd[r * CSTRIDE + tid];
        vals[tid] = a;
    }
    __syncthreads();
    if (tid == 0) {
        int nz = 0;
        double acc = 0.0;
#pragma unroll
        for (int b = 0; b < BINS; ++b) {
            double cnt = vals[b];
            double sm  = vals[BINS + b] * LN2;   // log2 units -> nats
            if (cnt > 0.0) { nz++; acc += sm / cnt; }
        }
        out[0] = (float)((nz > 0) ? (acc / (double)nz) : 0.0);
    }
}

extern "C" void kernel_launch(void* const* d_in, const int* in_sizes, int n_in,
                              void* d_out, int out_size, void* d_ws, size_t ws_size,
                              hipStream_t stream) {
    const float* pred = (const float*)d_in[0];   // [N,2] float32
    const int* target = (const int*)d_in[1];     // [N] int32 (harness lowers int64)
    const int nRows = in_sizes[1];
    const int nF4 = nRows / 2;
    double* wsd = (double*)d_ws;
    float* out = (float*)d_out;

    ghmc_init<<<1, 256, 0, stream>>>(wsd);
    ghmc_main<<<GRID, BLOCK, 0, stream>>>(
        (const float4*)pred, (const int2*)target, wsd, nF4, nRows);
    ghmc_fin<<<1, 64, 0, stream>>>(wsd, out);
}